// Round 1
// 2145.910 us; speedup vs baseline: 1.2512x; 1.2512x over previous
//
#include <hip/hip_runtime.h>

// ---------------- problem constants ----------------
#define NUSER 200000
#define NPROD 100000
#define NCAT    2000
#define NQRY   50000
#define EBUYS  500000
#define ESEARCH 300000
#define EMATCH  300000
#define EIN     100000

// type ids: 0=user 1=product 2=category 3=query
// relations t=0..7 (weight-stack index):
//  t0 user->product, t1 product->user, t2 user->query, t3 query->user,
//  t4 query->product, t5 product->query, t6 product->category, t7 category->product
// per-dst relation slots (must match wt_build's relsD):
//  user: {t1,t3}  product: {t0,t4,t7}  category: {t6}  query: {t2,t5}

// ---------------- CSR build ----------------
__global__ __launch_bounds__(256) void count_kernel(const int* __restrict__ dst, int E,
                                                    int* __restrict__ cnt) {
    int i = blockIdx.x * 256 + threadIdx.x;
    if (i < E) atomicAdd(&cnt[dst[i]], 1);
}

__global__ __launch_bounds__(256) void scan_partial(const int* __restrict__ cnt, int n,
                                                    int* __restrict__ bsums) {
    __shared__ int sd[256];
    int base = blockIdx.x * 4096;
    int s = 0;
    for (int j = threadIdx.x; j < 4096; j += 256) {
        int idx = base + j;
        s += (idx < n) ? cnt[idx] : 0;
    }
    sd[threadIdx.x] = s;
    __syncthreads();
    for (int st = 128; st > 0; st >>= 1) {
        if (threadIdx.x < st) sd[threadIdx.x] += sd[threadIdx.x + st];
        __syncthreads();
    }
    if (threadIdx.x == 0) bsums[blockIdx.x] = sd[0];
}

__global__ __launch_bounds__(64) void scan_bsums(int* __restrict__ bs, int nb) {
    int lane = threadIdx.x;
    int orig = (lane < nb) ? bs[lane] : 0;
    int v = orig;
    for (int off = 1; off < 64; off <<= 1) {
        int t = __shfl_up(v, off);
        if (lane >= off) v += t;
    }
    if (lane < nb) bs[lane] = v - orig;  // exclusive
}

__global__ __launch_bounds__(256) void scan_final(const int* __restrict__ cnt, int n,
                                                  const int* __restrict__ bsums,
                                                  int* __restrict__ offs) {
    __shared__ int tsum[256];
    int base = blockIdx.x * 4096;
    int tid = threadIdx.x;
    int local[16];
    int s = 0;
#pragma unroll
    for (int j = 0; j < 16; ++j) {
        int idx = base + tid * 16 + j;
        int v = (idx < n) ? cnt[idx] : 0;
        s += v;
        local[j] = s;
    }
    tsum[tid] = s;
    __syncthreads();
    int v = s;
    for (int off = 1; off < 256; off <<= 1) {
        int t = (tid >= off) ? tsum[tid - off] : 0;
        __syncthreads();
        v += t;
        tsum[tid] = v;
        __syncthreads();
    }
    int tpre = v - s;
    int bpre = bsums[blockIdx.x];
#pragma unroll
    for (int j = 0; j < 16; ++j) {
        int idx = base + tid * 16 + j;
        if (idx < n) offs[idx + 1] = bpre + tpre + local[j];
    }
    if (blockIdx.x == 0 && tid == 0) offs[0] = 0;
}

__global__ __launch_bounds__(256) void fill_kernel(const int* __restrict__ src,
                                                   const int* __restrict__ dst,
                                                   const float* __restrict__ w, int E,
                                                   const int* __restrict__ offs,
                                                   int* __restrict__ fill,
                                                   int* __restrict__ csr_src,
                                                   float* __restrict__ csr_w) {
    int i = blockIdx.x * 256 + threadIdx.x;
    if (i >= E) return;
    int d = dst[i];
    int slot = offs[d] + atomicAdd(&fill[d], 1);
    csr_src[slot] = src[i];
    csr_w[slot] = w[i];
}

// ---------------- f32 -> bf16 hi/lo split helpers ----------------
// hi = truncated top 16 bits (exact bf16); lo = bf16(trunc) of residual.
// a ~= hi + lo with relative error ~2^-16; dropped lo*lo term in the GEMM is
// ~2^-16 relative => result is f32-equivalent for this problem's magnitudes.
__device__ __forceinline__ unsigned pk_hi(float a, float b) {
    return (__float_as_uint(b) & 0xffff0000u) | (__float_as_uint(a) >> 16);
}
__device__ __forceinline__ float f32_trunc(float a) {
    return __uint_as_float(__float_as_uint(a) & 0xffff0000u);
}

// ---------------- fused weight build ----------------
// Produces bf16 hi/lo planes of the concat-K B matrix in N-MAJOR layout:
//   WH/WL[(l,d) base + n*K_d + s*128 + in], K_d = (1+nrel_d)*128.
// N-major B == original W row-major (B[k][n] = W[n][in]) -> no transpose needed.
// Block 0 (s=0) is sum_t Wl[t]; block s>=1 is Wr[rels[s-1]].
// Also writes bsum[(l*4+d)*128].
__global__ __launch_bounds__(256) void wt_build(const float* __restrict__ W1_l,
                                                const float* __restrict__ b1,
                                                const float* __restrict__ W1_r,
                                                const float* __restrict__ W2_l,
                                                const float* __restrict__ b2,
                                                const float* __restrict__ W2_r,
                                                unsigned short* __restrict__ WH,
                                                unsigned short* __restrict__ WL,
                                                float* __restrict__ bsum) {
    const int relsD[4][3] = {{1, 3, -1}, {0, 4, 7}, {6, -1, -1}, {2, 5, -1}};
    const int nrelD[4] = {2, 3, 1, 2};
    const int pre[4] = {0, 49152, 114688, 147456};  // elements, per-layer prefix
    int bid = blockIdx.x;
    int l = bid / 12, r = bid % 12;
    int d, s;
    if (r < 3) { d = 0; s = r; }
    else if (r < 7) { d = 1; s = r - 3; }
    else if (r < 9) { d = 2; s = r - 7; }
    else { d = 3; s = r - 9; }
    const float* Wl = l ? W2_l : W1_l;
    const float* Wr = l ? W2_r : W1_r;
    const float* bb = l ? b2 : b1;
    int K = (1 + nrelD[d]) * 128;
    size_t base = (size_t)l * 196608 + pre[d];
    if (s == 0 && threadIdx.x < 128) {
        float acc = 0.f;
        for (int j = 0; j < nrelD[d]; ++j) acc += bb[relsD[d][j] * 128 + threadIdx.x];
        bsum[(l * 4 + d) * 128 + threadIdx.x] = acc;
    }
    // 128 n x 128 in elements; 8-elem chunks: 2048 chunks / 256 threads = 8 iters
    for (int p = 0; p < 8; ++p) {
        int c = threadIdx.x + p * 256;
        int n = c >> 4, ic = (c & 15) * 8;
        float e[8];
        if (s == 0) {
#pragma unroll
            for (int q = 0; q < 8; ++q) e[q] = 0.f;
            for (int j = 0; j < nrelD[d]; ++j) {
                const float* wsrc = Wl + relsD[d][j] * 16384 + n * 128 + ic;
#pragma unroll
                for (int q = 0; q < 8; ++q) e[q] += wsrc[q];
            }
        } else {
            const float* wsrc = Wr + relsD[d][s - 1] * 16384 + n * 128 + ic;
#pragma unroll
            for (int q = 0; q < 8; ++q) e[q] = wsrc[q];
        }
        uint4 hi, lo;
        hi.x = pk_hi(e[0], e[1]); hi.y = pk_hi(e[2], e[3]);
        hi.z = pk_hi(e[4], e[5]); hi.w = pk_hi(e[6], e[7]);
        float lv[8];
#pragma unroll
        for (int q = 0; q < 8; ++q) lv[q] = e[q] - f32_trunc(e[q]);
        lo.x = pk_hi(lv[0], lv[1]); lo.y = pk_hi(lv[2], lv[3]);
        lo.z = pk_hi(lv[4], lv[5]); lo.w = pk_hi(lv[6], lv[7]);
        size_t go = base + (size_t)n * K + s * 128 + ic;
        *(uint4*)(WH + go) = hi;
        *(uint4*)(WL + go) = lo;
    }
}

// ---------------- CSR gather-reduce (scatter-mean) into concat-slot layout ----------
__global__ __launch_bounds__(256) void agg_kernel(const float* __restrict__ X, int ldx,
                                                  const int* __restrict__ offs,
                                                  const int* __restrict__ csr_src,
                                                  const float* __restrict__ csr_w,
                                                  float* __restrict__ out, int ldo,
                                                  int n_dst) {
    int row = blockIdx.x * 8 + (threadIdx.x >> 5);
    if (row >= n_dst) return;
    int lane = threadIdx.x & 31;
    int b = offs[row], e = offs[row + 1];
    float4 a = {0.f, 0.f, 0.f, 0.f};
    for (int i = b; i < e; ++i) {
        int s = csr_src[i];
        float w = csr_w[i];
        const float4 v = *(const float4*)(X + (size_t)s * ldx + lane * 4);
        a.x += w * v.x;
        a.y += w * v.y;
        a.z += w * v.z;
        a.w += w * v.w;
    }
    float inv = (e > b) ? 1.f / (float)(e - b) : 0.f;
    a.x *= inv; a.y *= inv; a.z *= inv; a.w *= inv;
    *(float4*)(out + (size_t)row * ldo + lane * 4) = a;
}

// ---------------- fused concat-K MFMA GEMM: Y = relu?([self|agg] @ W^T + bias) ------
// Split-bf16 (hi/lo) f32 emulation on v_mfma_f32_16x16x32_bf16:
//   C = Ah*Bh + Ah*Bl + Al*Bh  (f32 accumulate; dropped Al*Bl ~ 2^-16 rel)
// Tile: BM=128, BN=128, BK=64. 256 threads = 4 waves; wave w owns rows w*32..w*32+31
// as 2 m-frags x 8 n-frags of 16x16 accumulators.
// LDS: A hi/lo + B hi/lo planes [128][64] bf16, XOR-swizzled (idx ^= (row&7)<<3 in
// shorts) to kill the 128B-row-stride bank conflict on ds_read_b128 (G4).
typedef short bf16x8 __attribute__((ext_vector_type(8)));
typedef float f32x4 __attribute__((ext_vector_type(4)));

__global__ __launch_bounds__(256) void gemm_fused(const float* __restrict__ Xself, int lds_,
                                                  const float* __restrict__ Xagg, int lda_,
                                                  const unsigned short* __restrict__ WH,
                                                  const unsigned short* __restrict__ WL,
                                                  const float* __restrict__ bias,
                                                  float* __restrict__ Y, int ldy,
                                                  int M, int K, int relu) {
    __shared__ unsigned short sAh[8192];  // [128][64] bf16, swizzled
    __shared__ unsigned short sAl[8192];
    __shared__ unsigned short sBh[8192];  // [n=128][64] bf16, swizzled
    __shared__ unsigned short sBl[8192];
    int tid = threadIdx.x;
    int lane = tid & 63;
    int wave = tid >> 6;  // 0..3
    int m0 = blockIdx.x * 128;

    f32x4 acc[2][8] = {};  // [m-frag][n-frag]

    float bv[8];
#pragma unroll
    for (int g = 0; g < 8; ++g) bv[g] = bias[g * 16 + (lane & 15)];

    for (int kt = 0; kt < K; kt += 64) {
        const float* Xsrc;
        int ldx, kc0;
        if (kt < 128) { Xsrc = Xself; ldx = lds_; kc0 = kt; }
        else { Xsrc = Xagg; ldx = lda_; kc0 = kt - 128; }
        __syncthreads();  // protect previous iteration's LDS reads
        // ---- stage A: 128 rows x 64 k, f32 -> hi/lo bf16. float4 chunks:
        // 2048 chunks / 256 threads = 8 iters; lanes 0-15 cover one row (coalesced).
#pragma unroll
        for (int p = 0; p < 8; ++p) {
            int q = tid + p * 256;
            int m = q >> 4, kc = (q & 15) * 4;
            int gm = m0 + m;
            float4 v = {0.f, 0.f, 0.f, 0.f};
            if (gm < M) v = *(const float4*)(Xsrc + (size_t)gm * ldx + kc0 + kc);
            uint2 hi, lo;
            hi.x = pk_hi(v.x, v.y);
            hi.y = pk_hi(v.z, v.w);
            float l0 = v.x - f32_trunc(v.x), l1 = v.y - f32_trunc(v.y);
            float l2 = v.z - f32_trunc(v.z), l3 = v.w - f32_trunc(v.w);
            lo.x = pk_hi(l0, l1);
            lo.y = pk_hi(l2, l3);
            int sidx = (m * 64 + kc) ^ ((m & 7) << 3);
            *(uint2*)&sAh[sidx] = hi;
            *(uint2*)&sAl[sidx] = lo;
        }
        // ---- stage B: pre-split bf16 planes, pure copy. 16B chunks:
        // 1024 chunks/plane / 256 threads = 4 iters per plane.
#pragma unroll
        for (int p = 0; p < 4; ++p) {
            int q = tid + p * 256;
            int n = q >> 3, kc = (q & 7) * 8;
            int sidx = (n * 64 + kc) ^ ((n & 7) << 3);
            size_t go = (size_t)n * K + kt + kc;
            *(uint4*)&sBh[sidx] = *(const uint4*)(WH + go);
            *(uint4*)&sBl[sidx] = *(const uint4*)(WL + go);
        }
        __syncthreads();
        // ---- compute: 2 k-steps of 32
#pragma unroll
        for (int ks = 0; ks < 2; ++ks) {
            int kb = ks * 32 + (lane >> 4) * 8;  // lane's k base within tile
            bf16x8 ah[2], al[2];
#pragma unroll
            for (int f = 0; f < 2; ++f) {
                int m = wave * 32 + f * 16 + (lane & 15);
                int sidx = (m * 64 + kb) ^ ((m & 7) << 3);
                ah[f] = *(bf16x8*)&sAh[sidx];
                al[f] = *(bf16x8*)&sAl[sidx];
            }
#pragma unroll
            for (int g = 0; g < 8; ++g) {
                int n = g * 16 + (lane & 15);
                int sidx = (n * 64 + kb) ^ ((n & 7) << 3);
                bf16x8 bh = *(bf16x8*)&sBh[sidx];
                bf16x8 bl = *(bf16x8*)&sBl[sidx];
#pragma unroll
                for (int f = 0; f < 2; ++f) {
                    acc[f][g] = __builtin_amdgcn_mfma_f32_16x16x32_bf16(ah[f], bh, acc[f][g], 0, 0, 0);
                    acc[f][g] = __builtin_amdgcn_mfma_f32_16x16x32_bf16(ah[f], bl, acc[f][g], 0, 0, 0);
                    acc[f][g] = __builtin_amdgcn_mfma_f32_16x16x32_bf16(al[f], bh, acc[f][g], 0, 0, 0);
                }
            }
        }
    }
    // ---- epilogue: C/D layout col=lane&15, row=(lane>>4)*4+reg (m89-verified)
    int rbase = m0 + wave * 32 + (lane >> 4) * 4;
    int cl = lane & 15;
#pragma unroll
    for (int f = 0; f < 2; ++f) {
#pragma unroll
        for (int r = 0; r < 4; ++r) {
            int row = rbase + f * 16 + r;
            if (row >= M) continue;
            float* yr = Y + (size_t)row * ldy + cl;
#pragma unroll
            for (int g = 0; g < 8; ++g) {
                float v = acc[f][g][r] + bv[g];
                if (relu) v = fmaxf(v, 0.f);
                yr[g * 16] = v;
            }
        }
    }
}

// ---------------- host orchestration ----------------
extern "C" void kernel_launch(void* const* d_in, const int* in_sizes, int n_in,
                              void* d_out, int out_size, void* d_ws, size_t ws_size,
                              hipStream_t stream) {
    const float* emb[4] = {(const float*)d_in[0], (const float*)d_in[1],
                           (const float*)d_in[2], (const float*)d_in[3]};
    const float* W1_l = (const float*)d_in[4];
    const float* b1 = (const float*)d_in[5];
    const float* W1_r = (const float*)d_in[6];
    const float* W2_l = (const float*)d_in[7];
    const float* b2 = (const float*)d_in[8];
    const float* W2_r = (const float*)d_in[9];
    const float* ew[8];
    for (int i = 0; i < 8; ++i) ew[i] = (const float*)d_in[10 + i];
    const int* ei_buys = (const int*)d_in[18];
    const int* ei_sea = (const int*)d_in[19];
    const int* ei_mat = (const int*)d_in[20];
    const int* ei_in = (const int*)d_in[21];

    const int NT[4] = {NUSER, NPROD, NCAT, NQRY};
    const int rowOff[4] = {0, NUSER, NUSER + NPROD, NUSER + NPROD + NCAT};
    const int nrelD[4] = {2, 3, 1, 2};
    const int wtPre[4] = {0, 49152, 114688, 147456};

    struct RelT { int s, d, slot, E; const int* src; const int* dst; const float* w; };
    // slot assignment must match wt_build relsD: user{1,3} product{0,4,7} cat{6} query{2,5}
    RelT rel[8] = {
        {0, 1, 0, EBUYS,   ei_buys,          ei_buys + EBUYS,  ew[0]},  // t0
        {1, 0, 0, EBUYS,   ei_buys + EBUYS,  ei_buys,          ew[1]},  // t1
        {0, 3, 0, ESEARCH, ei_sea,           ei_sea + ESEARCH, ew[2]},  // t2
        {3, 0, 1, ESEARCH, ei_sea + ESEARCH, ei_sea,           ew[3]},  // t3
        {3, 1, 1, EMATCH,  ei_mat,           ei_mat + EMATCH,  ew[4]},  // t4
        {1, 3, 1, EMATCH,  ei_mat + EMATCH,  ei_mat,           ew[5]},  // t5
        {1, 2, 0, EIN,     ei_in,            ei_in + EIN,      ew[6]},  // t6
        {2, 1, 2, EIN,     ei_in + EIN,      ei_in,            ew[7]},  // t7
    };

    // ---- workspace carve ----
    char* p = (char*)d_ws;
    auto carve = [&](size_t bytes) {
        char* r = p;
        p += (bytes + 255) & ~(size_t)255;
        return r;
    };
    int* offs[8];
    for (int t = 0; t < 8; ++t) offs[t] = (int*)carve(((size_t)NT[rel[t].d] + 1) * 4);
    size_t fillTot = 0;
    for (int t = 0; t < 8; ++t) fillTot += (size_t)NT[rel[t].d];
    int* fillBase = (int*)carve(fillTot * 4);
    int* fill[8];
    {
        size_t o = 0;
        for (int t = 0; t < 8; ++t) { fill[t] = fillBase + o; o += NT[rel[t].d]; }
    }
    size_t Etot = 0;
    int eoff[8];
    for (int t = 0; t < 8; ++t) { eoff[t] = (int)Etot; Etot += rel[t].E; }
    int* csr_src = (int*)carve(Etot * 4);
    float* csr_w = (float*)carve(Etot * 4);
    int* bsums = (int*)carve(64 * 4);
    unsigned short* WH = (unsigned short*)carve((size_t)2 * 196608 * 2);
    unsigned short* WL = (unsigned short*)carve((size_t)2 * 196608 * 2);
    float* bsum = (float*)carve((size_t)8 * 128 * 4);
    // concat aggregate buffer: per dst type, [n_d][128*k_d], all types resident
    size_t aoff[4];
    size_t atot = 0;
    for (int d = 0; d < 4; ++d) {
        aoff[d] = atot;
        atot += (size_t)NT[d] * 128 * nrelD[d];
    }
    float* aggbuf = (float*)carve(atot * 4);  // ~410.6 MB

    // ---- CSR build (once, reused by both layers) ----
    hipMemsetAsync(fillBase, 0, fillTot * 4, stream);
    for (int t = 0; t < 8; ++t)
        count_kernel<<<(rel[t].E + 255) / 256, 256, 0, stream>>>(rel[t].dst, rel[t].E, fill[t]);
    for (int t = 0; t < 8; ++t) {
        int n = NT[rel[t].d];
        int nb = (n + 4095) / 4096;
        scan_partial<<<nb, 256, 0, stream>>>(fill[t], n, bsums);
        scan_bsums<<<1, 64, 0, stream>>>(bsums, nb);
        scan_final<<<nb, 256, 0, stream>>>(fill[t], n, bsums, offs[t]);
    }
    hipMemsetAsync(fillBase, 0, fillTot * 4, stream);
    for (int t = 0; t < 8; ++t)
        fill_kernel<<<(rel[t].E + 255) / 256, 256, 0, stream>>>(
            rel[t].src, rel[t].dst, rel[t].w, rel[t].E, offs[t], fill[t],
            csr_src + eoff[t], csr_w + eoff[t]);

    // ---- fused split-bf16 weights + summed bias ----
    wt_build<<<24, 256, 0, stream>>>(W1_l, b1, W1_r, W2_l, b2, W2_r, WH, WL, bsum);

    float* dout = (float*)d_out;

    // ---- two layers; layer-0 output (h) lives in d_out, layer-1 GEMM is in-place ----
    for (int layer = 0; layer < 2; ++layer) {
        // all aggregations first (layer-1 must read h before GEMMs overwrite d_out)
        for (int t = 0; t < 8; ++t) {
            int sT = rel[t].s, dT = rel[t].d, n = NT[dT];
            const float* X = layer == 0 ? emb[sT] : dout + (size_t)rowOff[sT] * 128;
            agg_kernel<<<(n + 7) / 8, 256, 0, stream>>>(
                X, 128, offs[t], csr_src + eoff[t], csr_w + eoff[t],
                aggbuf + aoff[dT] + rel[t].slot * 128, 128 * nrelD[dT], n);
        }
        // one fused MFMA GEMM per dst type
        for (int d = 0; d < 4; ++d) {
            int n = NT[d];
            const float* self = layer == 0 ? emb[d] : dout + (size_t)rowOff[d] * 128;
            size_t woff = (size_t)layer * 196608 + wtPre[d];
            gemm_fused<<<(n + 127) / 128, 256, 0, stream>>>(
                self, 128, aggbuf + aoff[d], 128 * nrelD[d],
                WH + woff, WL + woff, bsum + (size_t)(layer * 4 + d) * 128,
                dout + (size_t)rowOff[d] * 128, 128, n, (1 + nrelD[d]) * 128,
                layer == 0 ? 1 : 0);
        }
    }
}